// Round 12
// baseline (1397.392 us; speedup 1.0000x reference)
//
#include <hip/hip_runtime.h>

// MHSA with relative position bias (Swin window attention), MI355X gfx950.
// B=2048 windows, N=49 tokens, C=1024, 16 heads x 64. fp16 MFMA, fp32 accum.
// Round 12: R11 with compile fix (cvt_pkrtz returns __fp16x2 -> bit_cast to int).
// GEMMs = Round-2/7 schedule (settled). Attention: swapped-QK^T
// (S^T = mfma(K,Q)) so each lane owns P-columns (n = l15):
//   - softmax reduce = 2 shfl_xor (16/32) per column-group: 16 shuffles/wave
//   - P -> PV A-frag IN REGISTERS (cvt_pkrtz pack + 2-shfl/1-sel permute)
//   - no K LDS, no P LDS -> LDS = 8KB (Vt only); zero barriers

typedef _Float16 f16;
typedef _Float16 f16x8 __attribute__((ext_vector_type(8)));
typedef _Float16 f16x4 __attribute__((ext_vector_type(4)));
typedef float f32x4 __attribute__((ext_vector_type(4)));

#define G1P(p) ((const __attribute__((address_space(1))) unsigned int*)(p))
#define L3P(p) ((__attribute__((address_space(3))) unsigned int*)(p))

static const size_t MROW_MAX = 100351;   // clamp for padded rows 49..63 (attn)

// ---------------- fp32 -> fp16 convert (vec4) ----------------
__global__ void cvt_kernel(const float* __restrict__ in, f16* __restrict__ out, int n4) {
  int i = blockIdx.x * blockDim.x + threadIdx.x;
  int stride = gridDim.x * blockDim.x;
  const float4* in4 = (const float4*)in;
  f16x4* out4 = (f16x4*)out;
  for (; i < n4; i += stride) {
    float4 v = in4[i];
    f16x4 o = { (f16)v.x, (f16)v.y, (f16)v.z, (f16)v.w };
    out4[i] = o;
  }
}

// ---------------- bias table: f16 bias_t[h][n][m] = log2e*bias(n,m); mask=-60000 ----
__global__ void bias_kernel(const float* __restrict__ rpb, f16* __restrict__ bias_t) {
  int h = blockIdx.x;
  for (int e = threadIdx.x; e < 4096; e += blockDim.x) {
    int n = e >> 6, m = e & 63;
    float v = -60000.f;
    if (n < 49 && m < 49) {
      int in_ = n / 7, jn = n % 7, im = m / 7, jm = m % 7;
      v = rpb[h * 169 + (im - in_ + 6) * 13 + (jm - jn + 6)] * 1.44269504f;
    }
    bias_t[h * 4096 + e] = (f16)v;
  }
}

// ---------------- 256x256 8-phase GEMM (Round-2 verbatim; best measured) ----------
#define VM4 asm volatile("s_waitcnt vmcnt(4)" ::: "memory")
#define VM0 asm volatile("s_waitcnt vmcnt(0)" ::: "memory")
#define NOVM ((void)0)
#define NOSTG ((void)0)

#define STAGE(GB, ROW0, COL0, LDSOFF)                                              \
  {                                                                                \
    const f16* s0_ = (GB) + (size_t)((ROW0) + wid * 32 + srow) * K + ((COL0) + sce); \
    __builtin_amdgcn_global_load_lds(G1P(s0_), L3P(lds + (LDSOFF) + wid * 2048), 16, 0, 0); \
    const f16* s1_ = s0_ + (size_t)16 * K;                                         \
    __builtin_amdgcn_global_load_lds(G1P(s1_), L3P(lds + (LDSOFF) + wid * 2048 + 1024), 16, 0, 0); \
  }

#define MFMA4(AREG, ROW)                                                           \
  acc[ROW][0] = __builtin_amdgcn_mfma_f32_16x16x32_f16(AREG, b0, acc[ROW][0], 0, 0, 0); \
  acc[ROW][1] = __builtin_amdgcn_mfma_f32_16x16x32_f16(AREG, b1, acc[ROW][1], 0, 0, 0); \
  acc[ROW][2] = __builtin_amdgcn_mfma_f32_16x16x32_f16(AREG, b2, acc[ROW][2], 0, 0, 0); \
  acc[ROW][3] = __builtin_amdgcn_mfma_f32_16x16x32_f16(AREG, b3, acc[ROW][3], 0, 0, 0);

#define PHASE(ABASE, BBASE, MH, STG, VMW)                                          \
  {                                                                                \
    f16x8 a0 = *(const f16x8*)((ABASE) + (wm * 128 + (MH) * 64 +  0 + l15) * 64 + swz); \
    f16x8 a1 = *(const f16x8*)((ABASE) + (wm * 128 + (MH) * 64 + 16 + l15) * 64 + swz); \
    f16x8 a2 = *(const f16x8*)((ABASE) + (wm * 128 + (MH) * 64 + 32 + l15) * 64 + swz); \
    f16x8 a3 = *(const f16x8*)((ABASE) + (wm * 128 + (MH) * 64 + 48 + l15) * 64 + swz); \
    if ((MH) == 0) {                                                               \
      b0 = *(const f16x8*)((BBASE) + (wn * 64 +  0 + l15) * 64 + swz);             \
      b1 = *(const f16x8*)((BBASE) + (wn * 64 + 16 + l15) * 64 + swz);             \
      b2 = *(const f16x8*)((BBASE) + (wn * 64 + 32 + l15) * 64 + swz);             \
      b3 = *(const f16x8*)((BBASE) + (wn * 64 + 48 + l15) * 64 + swz);             \
    }                                                                              \
    STG;                                                                           \
    __builtin_amdgcn_s_barrier();                                                  \
    asm volatile("s_waitcnt lgkmcnt(0)" ::: "memory");                             \
    __builtin_amdgcn_sched_barrier(0);                                             \
    __builtin_amdgcn_s_setprio(1);                                                 \
    MFMA4(a0, (MH) * 4 + 0) MFMA4(a1, (MH) * 4 + 1)                                \
    MFMA4(a2, (MH) * 4 + 2) MFMA4(a3, (MH) * 4 + 3)                                \
    __builtin_amdgcn_s_setprio(0);                                                 \
    VMW;                                                                           \
    __builtin_amdgcn_s_barrier();                                                  \
  }

template <typename OutT>
__global__ __launch_bounds__(512, 2)
void gemm256(const f16* __restrict__ A, const f16* __restrict__ B,
             const float* __restrict__ bias, OutT* __restrict__ C,
             int N, int K, int ntiles_n) {
  __shared__ char lds[131072];
  const int tid = threadIdx.x;
  const int wid = tid >> 6, ln = tid & 63;
  const int l15 = ln & 15, lhi = ln >> 4;
  const int wm = wid >> 2, wn = wid & 3;
  const int srow = ln >> 2;
  const int sce = (((ln & 3) ^ ((ln >> 3) & 3)) << 3);
  const int swz = ((lhi ^ ((l15 >> 1) & 3)) << 4);

  const int nblk = gridDim.x;
  const int wg = (blockIdx.x & 7) * (nblk >> 3) + (blockIdx.x >> 3);
  const int bn = wg % ntiles_n, bm = wg / ntiles_n;
  const int m0 = bm * 256, n0 = bn * 256;

  f32x4 acc[8][4];
#pragma unroll
  for (int i = 0; i < 8; ++i)
#pragma unroll
    for (int j = 0; j < 4; ++j) acc[i][j] = (f32x4){0.f, 0.f, 0.f, 0.f};
  f16x8 b0, b1, b2, b3;

  STAGE(A, m0, 0, 0);
  STAGE(B, n0, 0, 32768);
  STAGE(A, m0, 32, 16384);
  STAGE(B, n0, 32, 49152);
  STAGE(A, m0, 64, 65536);
  STAGE(B, n0, 64, 98304);
  VM4;
  __builtin_amdgcn_s_barrier();

  for (int i = 0; i < 7; ++i) {
    const int cT1k1 = (2 * i + 1) * 64 + 32;
    const int cT2k0 = (2 * i + 2) * 64;
    const int cT2k1 = cT2k0 + 32;
    const int cT3k0 = (2 * i + 3) * 64;
    PHASE(lds + 0,      lds + 32768,  0, STAGE(A, m0, cT1k1, 81920),  NOVM);
    PHASE(lds + 0,      lds + 32768,  1, STAGE(B, n0, cT1k1, 114688), NOVM);
    PHASE(lds + 16384,  lds + 49152,  0, STAGE(A, m0, cT2k0, 0),      NOVM);
    PHASE(lds + 16384,  lds + 49152,  1, STAGE(B, n0, cT2k0, 32768),  VM4);
    PHASE(lds + 65536,  lds + 98304,  0, STAGE(A, m0, cT2k1, 16384),  NOVM);
    PHASE(lds + 65536,  lds + 98304,  1, STAGE(B, n0, cT2k1, 49152),  NOVM);
    PHASE(lds + 81920,  lds + 114688, 0, STAGE(A, m0, cT3k0, 65536),  NOVM);
    PHASE(lds + 81920,  lds + 114688, 1, STAGE(B, n0, cT3k0, 98304),  VM4);
  }
  PHASE(lds + 0,      lds + 32768,  0, STAGE(A, m0, 15 * 64 + 32, 81920),  NOVM);
  PHASE(lds + 0,      lds + 32768,  1, STAGE(B, n0, 15 * 64 + 32, 114688), NOVM);
  PHASE(lds + 16384,  lds + 49152,  0, NOSTG, NOVM);
  PHASE(lds + 16384,  lds + 49152,  1, NOSTG, VM0);
  PHASE(lds + 65536,  lds + 98304,  0, NOSTG, NOVM);
  PHASE(lds + 65536,  lds + 98304,  1, NOSTG, NOVM);
  PHASE(lds + 81920,  lds + 114688, 0, NOSTG, NOVM);
  PHASE(lds + 81920,  lds + 114688, 1, NOSTG, NOVM);

  float bv[4];
#pragma unroll
  for (int j = 0; j < 4; ++j) bv[j] = bias[n0 + wn * 64 + j * 16 + l15];
#pragma unroll
  for (int ii = 0; ii < 8; ++ii)
#pragma unroll
    for (int j = 0; j < 4; ++j)
#pragma unroll
      for (int r = 0; r < 4; ++r) {
        int gr = m0 + wm * 128 + ii * 16 + lhi * 4 + r;
        int gc = n0 + wn * 64 + j * 16 + l15;
        C[(size_t)gr * N + gc] = (OutT)(acc[ii][j][r] + bv[j]);
      }
}

// ---------------- attention: 1 wave per (window, head), swapped QK^T ----------------
// LDS 8KB = Vt only. S^T = mfma(K,Q): lane l15 = column n. Softmax per column:
// local 16-max + shfl_xor(16,32). P packed via cvt_pkrtz, permuted to PV A-frag
// in registers (2 shfl + 1 select per u32). Zero barriers.
__global__ __launch_bounds__(64, 4)
void attn_kernel(const f16* __restrict__ qkv,        // [MTOT][3072] q|k|v
                 const f16* __restrict__ bias_t,     // f16 [16][n][m], pre-scaled log2e
                 f16* __restrict__ out) {             // [MTOT][1024]
  __shared__ char lds[8192];
  const int bh = blockIdx.x;
  const int b = bh >> 4, h = bh & 15;
  const int ln = threadIdx.x;
  const int l15 = ln & 15, lhi = ln >> 4;
  const size_t base = (size_t)b * 49;

  // K frags (A-operand, rows m = t*16+l15)
  f16x8 kf[4][2];
#pragma unroll
  for (int t = 0; t < 4; ++t) {
    size_t row = base + t * 16 + l15;
    if (row > MROW_MAX) row = MROW_MAX;
    const f16* kp = qkv + row * 3072 + 1024 + h * 64 + lhi * 8;
    kf[t][0] = *(const f16x8*)(kp);
    kf[t][1] = *(const f16x8*)(kp + 32);
  }
  // Q frags (B-operand, cols n = u*16+l15)
  f16x8 qb[4][2];
#pragma unroll
  for (int u = 0; u < 4; ++u) {
    size_t row = base + u * 16 + l15;
    if (row > MROW_MAX) row = MROW_MAX;
    const f16* qp = qkv + row * 3072 + h * 64 + lhi * 8;
    qb[u][0] = *(const f16x8*)(qp);
    qb[u][1] = *(const f16x8*)(qp + 32);
  }
  // V rows
  size_t rowv = base + ln;
  if (rowv > MROW_MAX) rowv = MROW_MAX;
  const f16* vp = qkv + rowv * 3072 + 2048 + h * 64;
  f16x8 vr[8];
#pragma unroll
  for (int j = 0; j < 8; ++j) vr[j] = *(const f16x8*)(vp + j * 8);
  // bias: bq[u][t] = bias[n=u*16+l15][m = t*16+lhi*4 ..+4)
  const f16* bb = bias_t + h * 4096;
  f16x4 bq[4][4];
#pragma unroll
  for (int u = 0; u < 4; ++u)
#pragma unroll
    for (int t = 0; t < 4; ++t)
      bq[u][t] = *(const f16x4*)(bb + (u * 16 + l15) * 64 + t * 16 + lhi * 4);

  // V transpose into Vt[d][m] (compiler waits vr)
#pragma unroll
  for (int d = 0; d < 64; ++d)
    *(f16*)(lds + d * 128 + ((ln * 2) ^ ((d & 7) << 4))) = vr[d >> 3][d & 7];

  // per-u: S^T -> column softmax -> pack -> permute to PV A-frags
  const float SC = 0.125f * 1.44269504f;
  const int s0 = ((lhi & 1) * 2) * 16 + l15;   // src lane for j=0,1
  const int s1 = s0 + 16;                       // src lane for j=2,3
  const bool hi = (lhi >> 1) & 1;
  int afr[4][2][4];                             // [i][kk][u32 j]
#pragma unroll
  for (int u = 0; u < 4; ++u) {
    f32x4 acc[4];
#pragma unroll
    for (int t = 0; t < 4; ++t) acc[t] = (f32x4){0.f, 0.f, 0.f, 0.f};
#pragma unroll
    for (int kk = 0; kk < 2; ++kk) {
      __builtin_amdgcn_s_setprio(1);
#pragma unroll
      for (int t = 0; t < 4; ++t)
        acc[t] = __builtin_amdgcn_mfma_f32_16x16x32_f16(kf[t][kk], qb[u][kk], acc[t], 0, 0, 0);
      __builtin_amdgcn_s_setprio(0);
    }
    // softmax over column n = u*16+l15 (64 m-values: 16/lane x 4 lhi-lanes)
    float lv[4][4];
#pragma unroll
    for (int t = 0; t < 4; ++t)
#pragma unroll
      for (int r = 0; r < 4; ++r)
        lv[t][r] = acc[t][r] * SC + (float)bq[u][t][r];
    float Mx = lv[0][0];
#pragma unroll
    for (int t = 0; t < 4; ++t)
#pragma unroll
      for (int r = 0; r < 4; ++r) Mx = fmaxf(Mx, lv[t][r]);
    Mx = fmaxf(Mx, __shfl_xor(Mx, 16));
    Mx = fmaxf(Mx, __shfl_xor(Mx, 32));
    float s = 0.f;
#pragma unroll
    for (int t = 0; t < 4; ++t)
#pragma unroll
      for (int r = 0; r < 4; ++r) { lv[t][r] = exp2f(lv[t][r] - Mx); s += lv[t][r]; }
    s += __shfl_xor(s, 16);
    s += __shfl_xor(s, 32);
    float inv = 1.f / s;
    // pack P (column u's 16 values) into 8 u32
    int pk[4][2];
#pragma unroll
    for (int t = 0; t < 4; ++t)
#pragma unroll
      for (int pp = 0; pp < 2; ++pp)
        pk[t][pp] = __builtin_bit_cast(int,
            __builtin_amdgcn_cvt_pkrtz(lv[t][2 * pp] * inv, lv[t][2 * pp + 1] * inv));
    // permute: afr[u][kk][j] = pk[2kk+(lhi>>1)][j&1] from lane lhi_p=2(lhi&1)+(j>>1)
#pragma unroll
    for (int kk = 0; kk < 2; ++kk)
#pragma unroll
      for (int j = 0; j < 4; ++j) {
        int src = (j >> 1) ? s1 : s0;
        int a0 = __shfl(pk[kk * 2][j & 1], src);
        int a1 = __shfl(pk[kk * 2 + 1][j & 1], src);
        afr[u][kk][j] = hi ? a1 : a0;
      }
  }

  // O = P @ V (A-frags from registers, B-frags = Vt from LDS)
  f32x4 o[4][4];
#pragma unroll
  for (int i = 0; i < 4; ++i)
#pragma unroll
    for (int j = 0; j < 4; ++j) o[i][j] = (f32x4){0.f, 0.f, 0.f, 0.f};
#pragma unroll
  for (int kk = 0; kk < 2; ++kk) {
    f16x8 bf[4];
#pragma unroll
    for (int j = 0; j < 4; ++j) {
      int dr = j * 16 + l15;
      bf[j] = *(const f16x8*)(lds + dr * 128 + ((kk * 64 + lhi * 16) ^ ((dr & 7) << 4)));
    }
    __builtin_amdgcn_s_setprio(1);
#pragma unroll
    for (int i = 0; i < 4; ++i) {
      union { int w[4]; f16x8 v; } au;
#pragma unroll
      for (int j = 0; j < 4; ++j) au.w[j] = afr[i][kk][j];
#pragma unroll
      for (int j = 0; j < 4; ++j)
        o[i][j] = __builtin_amdgcn_mfma_f32_16x16x32_f16(au.v, bf[j], o[i][j], 0, 0, 0);
    }
    __builtin_amdgcn_s_setprio(0);
  }
#pragma unroll
  for (int i = 0; i < 4; ++i)
#pragma unroll
    for (int j = 0; j < 4; ++j)
#pragma unroll
      for (int r = 0; r < 4; ++r) {
        int n = i * 16 + lhi * 4 + r;
        if (n < 49)
          out[(base + n) * 1024 + h * 64 + j * 16 + l15] = (f16)o[i][j][r];
      }
}

extern "C" void kernel_launch(void* const* d_in, const int* in_sizes, int n_in,
                              void* d_out, int out_size, void* d_ws, size_t ws_size,
                              hipStream_t stream) {
  const float* x      = (const float*)d_in[0];  // [100352][1024]
  const float* qkv_w  = (const float*)d_in[1];  // [3072][1024]
  const float* qkv_b  = (const float*)d_in[2];  // [3072]
  const float* rpb    = (const float*)d_in[3];  // [16][13][13]
  const float* proj_w = (const float*)d_in[4];  // [1024][1024]
  const float* proj_b = (const float*)d_in[5];  // [1024]
  float* out = (float*)d_out;

  char* ws = (char*)d_ws;
  f16*   x16      = (f16*)(ws);                              // 205,520,896
  f16*   wq16     = (f16*)(ws + 205520896);                  //   6,291,456
  f16*   wp16     = (f16*)(ws + 211812352);                  //   2,097,152
  f16*   qkv16    = (f16*)(ws + 213909504);                  // 616,562,688
  f16*   attn16   = (f16*)(ws + 830472192);                  // 205,520,896
  f16*   bias_t   = (f16*)(ws + 1035993088);                 //     131,072

  cvt_kernel<<<2048, 256, 0, stream>>>(x, x16, 102760448 / 4);
  cvt_kernel<<<1024, 256, 0, stream>>>(qkv_w, wq16, 3145728 / 4);
  cvt_kernel<<<512, 256, 0, stream>>>(proj_w, wp16, 1048576 / 4);
  bias_kernel<<<16, 64, 0, stream>>>(rpb, bias_t);

  // qkv = x @ qkv_w^T + qkv_b   [100352][3072] fp16   (392 x 12 tiles)
  gemm256<f16><<<4704, 512, 0, stream>>>(x16, wq16, qkv_b, qkv16, 3072, 1024, 12);
  // attention: 1 wave per (window, head), swapped-QK^T in-register P
  attn_kernel<<<2048 * 16, 64, 0, stream>>>(qkv16, bias_t, attn16);
  // out = attn @ proj_w^T + proj_b   [100352][1024] fp32  (392 x 4 tiles)
  gemm256<float><<<1568, 512, 0, stream>>>(attn16, wp16, proj_b, out, 1024, 1024, 4);
}

// Round 13
// 1252.252 us; speedup vs baseline: 1.1159x; 1.1159x over previous
//
#include <hip/hip_runtime.h>

// MHSA with relative position bias (Swin window attention), MI355X gfx950.
// B=2048 windows, N=49 tokens, C=1024, 16 heads x 64. fp16 MFMA, fp32 accum.
// Round 13: attn compute = Round-10 verbatim (best measured ~280us); the change
// is DATA LAYOUT: GEMM1 writes qkv head-blocked [b][h][q|k|v][49][64] so each
// attention block reads 3 contiguous 6.2KB runs instead of 49 rows at 6KB
// stride (64B scattered sectors -> full-line HBM/L2 efficiency).
// GEMMs = Round-2/7 schedule (settled: ~670us, 43% MfmaUtil, 0 conflicts).

typedef _Float16 f16;
typedef _Float16 f16x8 __attribute__((ext_vector_type(8)));
typedef _Float16 f16x4 __attribute__((ext_vector_type(4)));
typedef float f32x4 __attribute__((ext_vector_type(4)));

#define G1P(p) ((const __attribute__((address_space(1))) unsigned int*)(p))
#define L3P(p) ((__attribute__((address_space(3))) unsigned int*)(p))

// ---------------- fp32 -> fp16 convert (vec4) ----------------
__global__ void cvt_kernel(const float* __restrict__ in, f16* __restrict__ out, int n4) {
  int i = blockIdx.x * blockDim.x + threadIdx.x;
  int stride = gridDim.x * blockDim.x;
  const float4* in4 = (const float4*)in;
  f16x4* out4 = (f16x4*)out;
  for (; i < n4; i += stride) {
    float4 v = in4[i];
    f16x4 o = { (f16)v.x, (f16)v.y, (f16)v.z, (f16)v.w };
    out4[i] = o;
  }
}

// ---------------- bias table: f16 bias_t[h][m][n] = log2e*bias(n,m); mask=-60000 ----
__global__ void bias_kernel(const float* __restrict__ rpb, f16* __restrict__ bias_t) {
  int h = blockIdx.x;
  for (int e = threadIdx.x; e < 4096; e += blockDim.x) {
    int m = e >> 6, n = e & 63;           // TRANSPOSED storage: [m][n]
    float v = -60000.f;                   // exp2(x-60000) == 0 in f32
    if (n < 49 && m < 49) {
      int in_ = n / 7, jn = n % 7, im = m / 7, jm = m % 7;
      v = rpb[h * 169 + (im - in_ + 6) * 13 + (jm - jn + 6)] * 1.44269504f;
    }
    bias_t[h * 4096 + e] = (f16)v;
  }
}

// ---------------- 256x256 8-phase GEMM (Round-2 schedule; best measured) ----------
// HB=true: epilogue writes head-blocked qkv layout [b][h][which][49][64].
#define VM4 asm volatile("s_waitcnt vmcnt(4)" ::: "memory")
#define VM0 asm volatile("s_waitcnt vmcnt(0)" ::: "memory")
#define NOVM ((void)0)
#define NOSTG ((void)0)

#define STAGE(GB, ROW0, COL0, LDSOFF)                                              \
  {                                                                                \
    const f16* s0_ = (GB) + (size_t)((ROW0) + wid * 32 + srow) * K + ((COL0) + sce); \
    __builtin_amdgcn_global_load_lds(G1P(s0_), L3P(lds + (LDSOFF) + wid * 2048), 16, 0, 0); \
    const f16* s1_ = s0_ + (size_t)16 * K;                                         \
    __builtin_amdgcn_global_load_lds(G1P(s1_), L3P(lds + (LDSOFF) + wid * 2048 + 1024), 16, 0, 0); \
  }

#define MFMA4(AREG, ROW)                                                           \
  acc[ROW][0] = __builtin_amdgcn_mfma_f32_16x16x32_f16(AREG, b0, acc[ROW][0], 0, 0, 0); \
  acc[ROW][1] = __builtin_amdgcn_mfma_f32_16x16x32_f16(AREG, b1, acc[ROW][1], 0, 0, 0); \
  acc[ROW][2] = __builtin_amdgcn_mfma_f32_16x16x32_f16(AREG, b2, acc[ROW][2], 0, 0, 0); \
  acc[ROW][3] = __builtin_amdgcn_mfma_f32_16x16x32_f16(AREG, b3, acc[ROW][3], 0, 0, 0);

#define PHASE(ABASE, BBASE, MH, STG, VMW)                                          \
  {                                                                                \
    f16x8 a0 = *(const f16x8*)((ABASE) + (wm * 128 + (MH) * 64 +  0 + l15) * 64 + swz); \
    f16x8 a1 = *(const f16x8*)((ABASE) + (wm * 128 + (MH) * 64 + 16 + l15) * 64 + swz); \
    f16x8 a2 = *(const f16x8*)((ABASE) + (wm * 128 + (MH) * 64 + 32 + l15) * 64 + swz); \
    f16x8 a3 = *(const f16x8*)((ABASE) + (wm * 128 + (MH) * 64 + 48 + l15) * 64 + swz); \
    if ((MH) == 0) {                                                               \
      b0 = *(const f16x8*)((BBASE) + (wn * 64 +  0 + l15) * 64 + swz);             \
      b1 = *(const f16x8*)((BBASE) + (wn * 64 + 16 + l15) * 64 + swz);             \
      b2 = *(const f16x8*)((BBASE) + (wn * 64 + 32 + l15) * 64 + swz);             \
      b3 = *(const f16x8*)((BBASE) + (wn * 64 + 48 + l15) * 64 + swz);             \
    }                                                                              \
    STG;                                                                           \
    __builtin_amdgcn_s_barrier();                                                  \
    asm volatile("s_waitcnt lgkmcnt(0)" ::: "memory");                             \
    __builtin_amdgcn_sched_barrier(0);                                             \
    __builtin_amdgcn_s_setprio(1);                                                 \
    MFMA4(a0, (MH) * 4 + 0) MFMA4(a1, (MH) * 4 + 1)                                \
    MFMA4(a2, (MH) * 4 + 2) MFMA4(a3, (MH) * 4 + 3)                                \
    __builtin_amdgcn_s_setprio(0);                                                 \
    VMW;                                                                           \
    __builtin_amdgcn_s_barrier();                                                  \
  }

template <typename OutT, bool HB>
__global__ __launch_bounds__(512, 2)
void gemm256(const f16* __restrict__ A, const f16* __restrict__ B,
             const float* __restrict__ bias, OutT* __restrict__ C,
             int N, int K, int ntiles_n) {
  __shared__ char lds[131072];
  const int tid = threadIdx.x;
  const int wid = tid >> 6, ln = tid & 63;
  const int l15 = ln & 15, lhi = ln >> 4;
  const int wm = wid >> 2, wn = wid & 3;
  const int srow = ln >> 2;
  const int sce = (((ln & 3) ^ ((ln >> 3) & 3)) << 3);
  const int swz = ((lhi ^ ((l15 >> 1) & 3)) << 4);

  const int nblk = gridDim.x;
  const int wg = (blockIdx.x & 7) * (nblk >> 3) + (blockIdx.x >> 3);
  const int bn = wg % ntiles_n, bm = wg / ntiles_n;
  const int m0 = bm * 256, n0 = bn * 256;

  f32x4 acc[8][4];
#pragma unroll
  for (int i = 0; i < 8; ++i)
#pragma unroll
    for (int j = 0; j < 4; ++j) acc[i][j] = (f32x4){0.f, 0.f, 0.f, 0.f};
  f16x8 b0, b1, b2, b3;

  STAGE(A, m0, 0, 0);
  STAGE(B, n0, 0, 32768);
  STAGE(A, m0, 32, 16384);
  STAGE(B, n0, 32, 49152);
  STAGE(A, m0, 64, 65536);
  STAGE(B, n0, 64, 98304);
  VM4;
  __builtin_amdgcn_s_barrier();

  for (int i = 0; i < 7; ++i) {
    const int cT1k1 = (2 * i + 1) * 64 + 32;
    const int cT2k0 = (2 * i + 2) * 64;
    const int cT2k1 = cT2k0 + 32;
    const int cT3k0 = (2 * i + 3) * 64;
    PHASE(lds + 0,      lds + 32768,  0, STAGE(A, m0, cT1k1, 81920),  NOVM);
    PHASE(lds + 0,      lds + 32768,  1, STAGE(B, n0, cT1k1, 114688), NOVM);
    PHASE(lds + 16384,  lds + 49152,  0, STAGE(A, m0, cT2k0, 0),      NOVM);
    PHASE(lds + 16384,  lds + 49152,  1, STAGE(B, n0, cT2k0, 32768),  VM4);
    PHASE(lds + 65536,  lds + 98304,  0, STAGE(A, m0, cT2k1, 16384),  NOVM);
    PHASE(lds + 65536,  lds + 98304,  1, STAGE(B, n0, cT2k1, 49152),  NOVM);
    PHASE(lds + 81920,  lds + 114688, 0, STAGE(A, m0, cT3k0, 65536),  NOVM);
    PHASE(lds + 81920,  lds + 114688, 1, STAGE(B, n0, cT3k0, 98304),  VM4);
  }
  PHASE(lds + 0,      lds + 32768,  0, STAGE(A, m0, 15 * 64 + 32, 81920),  NOVM);
  PHASE(lds + 0,      lds + 32768,  1, STAGE(B, n0, 15 * 64 + 32, 114688), NOVM);
  PHASE(lds + 16384,  lds + 49152,  0, NOSTG, NOVM);
  PHASE(lds + 16384,  lds + 49152,  1, NOSTG, VM0);
  PHASE(lds + 65536,  lds + 98304,  0, NOSTG, NOVM);
  PHASE(lds + 65536,  lds + 98304,  1, NOSTG, NOVM);
  PHASE(lds + 81920,  lds + 114688, 0, NOSTG, NOVM);
  PHASE(lds + 81920,  lds + 114688, 1, NOSTG, NOVM);

  float bv[4];
#pragma unroll
  for (int j = 0; j < 4; ++j) bv[j] = bias[n0 + wn * 64 + j * 16 + l15];
#pragma unroll
  for (int ii = 0; ii < 8; ++ii)
#pragma unroll
    for (int r = 0; r < 4; ++r) {
      int gr = m0 + wm * 128 + ii * 16 + lhi * 4 + r;
      if (HB) {
        int bw = gr / 49, n = gr - bw * 49;   // window, token
#pragma unroll
        for (int j = 0; j < 4; ++j) {
          int gc = n0 + wn * 64 + j * 16 + l15;
          int which = gc >> 10, rem = gc & 1023;
          int h = rem >> 6, d = rem & 63;
          size_t addr = (((size_t)bw * 16 + h) * 3 + which) * 3136 + n * 64 + d;
          C[addr] = (OutT)(acc[ii][j][r] + bv[j]);
        }
      } else {
#pragma unroll
        for (int j = 0; j < 4; ++j) {
          int gc = n0 + wn * 64 + j * 16 + l15;
          C[(size_t)gr * N + gc] = (OutT)(acc[ii][j][r] + bv[j]);
        }
      }
    }
}

// ---------------- attention: 1 wave per (window, head), zero barriers ----------------
// (Round-10 compute verbatim; head-blocked qkv addressing.)
// LDS 16KB: K then P [0,8K), Vt [8K,16K). All global loads issued up front;
// one vmcnt(0) drain; per-wave in-order DS gives all remaining ordering.
__global__ __launch_bounds__(64)
void attn_kernel(const f16* __restrict__ qkv,        // [b][h][q|k|v][49][64]
                 const f16* __restrict__ bias_t,     // f16 [16][m][n], pre-scaled log2e
                 f16* __restrict__ out) {             // [MTOT][1024]
  __shared__ char lds[16384];
  const int bh = blockIdx.x;
  const int b = bh >> 4, h = bh & 15;
  const int ln = threadIdx.x;
  const int l15 = ln & 15, lhi = ln >> 4;
  const size_t base = (size_t)b * 49;
  const size_t qb = (size_t)bh * 3 * 3136;   // q block
  const size_t kb = qb + 3136;               // k block
  const size_t vb = qb + 6272;               // v block

  // --- issue K staging (8x global_load_lds; contiguous 128B rows) ---
  {
    int rA = ln >> 3, lc = ln & 7;
#pragma unroll
    for (int c = 0; c < 8; ++c) {
      int r = c * 8 + rA;
      int rc = r > 48 ? 48 : r;
      int ce = (lc ^ (r & 7)) << 3;
      const f16* g = qkv + kb + rc * 64 + ce;
      __builtin_amdgcn_global_load_lds(G1P(g), L3P(lds + c * 1024), 16, 0, 0);
    }
  }

  // --- issue V loads (8x b128; one contiguous 8KB block per wave) ---
  int rv = ln > 48 ? 48 : ln;
  const f16* vp = qkv + vb + rv * 64;
  f16x8 vr[8];
#pragma unroll
  for (int j = 0; j < 8; ++j) vr[j] = *(const f16x8*)(vp + j * 8);

  // --- issue Q loads (8x b128) ---
  f16x8 qf[4][2];
#pragma unroll
  for (int t = 0; t < 4; ++t) {
    int rq = t * 16 + l15;
    if (rq > 48) rq = 48;
    const f16* qp = qkv + qb + rq * 64 + lhi * 8;
    qf[t][0] = *(const f16x8*)(qp);
    qf[t][1] = *(const f16x8*)(qp + 32);
  }

  // --- issue bias loads (16x f16x4): bq[i][j] = bias[m=j*16+l15][n=i*16+lhi*4 ..+4) ---
  const f16* bb = bias_t + h * 4096;
  f16x4 bq[4][4];
#pragma unroll
  for (int i = 0; i < 4; ++i)
#pragma unroll
    for (int j = 0; j < 4; ++j)
      bq[i][j] = *(const f16x4*)(bb + (j * 16 + l15) * 64 + i * 16 + lhi * 4);

  // --- V transpose into Vt (compiler waits vr) ---
#pragma unroll
  for (int d = 0; d < 64; ++d)
    *(f16*)(lds + 8192 + d * 128 + ((ln * 2) ^ ((d & 7) << 4))) = vr[d >> 3][d & 7];

  // --- single drain: K LDS deposit + all reg loads complete ---
  asm volatile("s_waitcnt vmcnt(0)" ::: "memory");
  __builtin_amdgcn_sched_barrier(0);

  // --- S = Q @ K^T (K frags from LDS) ---
  f32x4 acc[4][4];
#pragma unroll
  for (int i = 0; i < 4; ++i)
#pragma unroll
    for (int j = 0; j < 4; ++j) acc[i][j] = (f32x4){0.f, 0.f, 0.f, 0.f};
#pragma unroll
  for (int kk = 0; kk < 2; ++kk) {
    f16x8 bf[4];
#pragma unroll
    for (int t = 0; t < 4; ++t) {
      int mr = t * 16 + l15;
      int pb = (kk * 64 + lhi * 16) ^ ((mr & 7) << 4);
      bf[t] = *(const f16x8*)(lds + mr * 128 + pb);
    }
    __builtin_amdgcn_s_setprio(1);
#pragma unroll
    for (int i = 0; i < 4; ++i)
#pragma unroll
      for (int j = 0; j < 4; ++j)
        acc[i][j] = __builtin_amdgcn_mfma_f32_16x16x32_f16(qf[i][kk], bf[j], acc[i][j], 0, 0, 0);
    __builtin_amdgcn_s_setprio(0);
  }

  // --- softmax (base-2; bias already in regs); P overwrites K region ---
  const float SC = 0.125f * 1.44269504f;
#pragma unroll
  for (int i = 0; i < 4; ++i) {
#pragma unroll
    for (int r = 0; r < 4; ++r) {
      int n = i * 16 + lhi * 4 + r;
      float lv[4];
#pragma unroll
      for (int j = 0; j < 4; ++j)
        lv[j] = acc[i][j][r] * SC + (float)bq[i][j][r];
      float Mx = fmaxf(fmaxf(lv[0], lv[1]), fmaxf(lv[2], lv[3]));
#pragma unroll
      for (int off = 1; off < 16; off <<= 1) Mx = fmaxf(Mx, __shfl_xor(Mx, off));
      float s = 0.f;
#pragma unroll
      for (int j = 0; j < 4; ++j) { lv[j] = exp2f(lv[j] - Mx); s += lv[j]; }
#pragma unroll
      for (int off = 1; off < 16; off <<= 1) s += __shfl_xor(s, off);
      float inv = 1.f / s;
#pragma unroll
      for (int j = 0; j < 4; ++j) {
        int m = j * 16 + l15;
        *(f16*)(lds + n * 128 + ((m * 2) ^ ((n & 7) << 4))) = (f16)(lv[j] * inv);
      }
    }
  }
  // per-wave in-order DS: P writes retire before the P reads below

  // --- O = P @ V ---
  f32x4 o[4][4];
#pragma unroll
  for (int i = 0; i < 4; ++i)
#pragma unroll
    for (int j = 0; j < 4; ++j) o[i][j] = (f32x4){0.f, 0.f, 0.f, 0.f};
#pragma unroll
  for (int kk = 0; kk < 2; ++kk) {
    f16x8 af[4], bf[4];
#pragma unroll
    for (int t = 0; t < 4; ++t) {
      int nr = t * 16 + l15;
      int pb = (kk * 64 + lhi * 16) ^ ((nr & 7) << 4);
      af[t] = *(const f16x8*)(lds + nr * 128 + pb);
      bf[t] = *(const f16x8*)(lds + 8192 + nr * 128 + pb);
    }
    __builtin_amdgcn_s_setprio(1);
#pragma unroll
    for (int i = 0; i < 4; ++i)
#pragma unroll
      for (int j = 0; j < 4; ++j)
        o[i][j] = __builtin_amdgcn_mfma_f32_16x16x32_f16(af[i], bf[j], o[i][j], 0, 0, 0);
    __builtin_amdgcn_s_setprio(0);
  }
#pragma unroll
  for (int i = 0; i < 4; ++i)
#pragma unroll
    for (int j = 0; j < 4; ++j)
#pragma unroll
      for (int r = 0; r < 4; ++r) {
        int n = i * 16 + lhi * 4 + r;
        if (n < 49)
          out[(base + n) * 1024 + h * 64 + j * 16 + l15] = (f16)o[i][j][r];
      }
}

extern "C" void kernel_launch(void* const* d_in, const int* in_sizes, int n_in,
                              void* d_out, int out_size, void* d_ws, size_t ws_size,
                              hipStream_t stream) {
  const float* x      = (const float*)d_in[0];  // [100352][1024]
  const float* qkv_w  = (const float*)d_in[1];  // [3072][1024]
  const float* qkv_b  = (const float*)d_in[2];  // [3072]
  const float* rpb    = (const float*)d_in[3];  // [16][13][13]
  const float* proj_w = (const float*)d_in[4];  // [1024][1024]
  const float* proj_b = (const float*)d_in[5];  // [1024]
  float* out = (float*)d_out;

  char* ws = (char*)d_ws;
  f16*   x16      = (f16*)(ws);                              // 205,520,896
  f16*   wq16     = (f16*)(ws + 205520896);                  //   6,291,456
  f16*   wp16     = (f16*)(ws + 211812352);                  //   2,097,152
  f16*   qkv16    = (f16*)(ws + 213909504);                  // 616,562,688 (head-blocked)
  f16*   attn16   = (f16*)(ws + 830472192);                  // 205,520,896
  f16*   bias_t   = (f16*)(ws + 1035993088);                 //     131,072

  cvt_kernel<<<2048, 256, 0, stream>>>(x, x16, 102760448 / 4);
  cvt_kernel<<<1024, 256, 0, stream>>>(qkv_w, wq16, 3145728 / 4);
  cvt_kernel<<<512, 256, 0, stream>>>(proj_w, wp16, 1048576 / 4);
  bias_kernel<<<16, 64, 0, stream>>>(rpb, bias_t);

  // qkv = x @ qkv_w^T + qkv_b -> head-blocked [b][h][q|k|v][49][64] fp16
  gemm256<f16, true><<<4704, 512, 0, stream>>>(x16, wq16, qkv_b, qkv16, 3072, 1024, 12);
  // attention: 1 wave per (window, head), latency-optimized (R10 compute)
  attn_kernel<<<2048 * 16, 64, 0, stream>>>(qkv16, bias_t, attn16);
  // out = attn @ proj_w^T + proj_b   [100352][1024] fp32  (392 x 4 tiles)
  gemm256<float, false><<<1568, 512, 0, stream>>>(attn16, wp16, proj_b, out, 1024, 1024, 4);
}

// Round 14
// 1236.531 us; speedup vs baseline: 1.1301x; 1.0127x over previous
//
#include <hip/hip_runtime.h>

// MHSA with relative position bias (Swin window attention), MI355X gfx950.
// B=2048 windows, N=49 tokens, C=1024, 16 heads x 64. fp16 MFMA, fp32 accum.
// Round 14: extend head-blocked layout across the attn->GEMM2 boundary:
// attn writes attnHB[b][h][49][64] (one contiguous 6.2KB run per block);
// GEMM2 remaps its A-source (row,col)->(row/49, col>>6, row%49, col&63)
// inside global_load_lds addressing (quad still reads 64B contiguous).
// GEMM schedule = Round-2 (settled); attn compute = Round-10 (settled).

typedef _Float16 f16;
typedef _Float16 f16x8 __attribute__((ext_vector_type(8)));
typedef _Float16 f16x4 __attribute__((ext_vector_type(4)));
typedef float f32x4 __attribute__((ext_vector_type(4)));

#define G1P(p) ((const __attribute__((address_space(1))) unsigned int*)(p))
#define L3P(p) ((__attribute__((address_space(3))) unsigned int*)(p))

// ---------------- fp32 -> fp16 convert (vec4) ----------------
__global__ void cvt_kernel(const float* __restrict__ in, f16* __restrict__ out, int n4) {
  int i = blockIdx.x * blockDim.x + threadIdx.x;
  int stride = gridDim.x * blockDim.x;
  const float4* in4 = (const float4*)in;
  f16x4* out4 = (f16x4*)out;
  for (; i < n4; i += stride) {
    float4 v = in4[i];
    f16x4 o = { (f16)v.x, (f16)v.y, (f16)v.z, (f16)v.w };
    out4[i] = o;
  }
}

// ---------------- bias table: f16 bias_t[h][m][n] = log2e*bias(n,m); mask=-60000 ----
__global__ void bias_kernel(const float* __restrict__ rpb, f16* __restrict__ bias_t) {
  int h = blockIdx.x;
  for (int e = threadIdx.x; e < 4096; e += blockDim.x) {
    int m = e >> 6, n = e & 63;           // TRANSPOSED storage: [m][n]
    float v = -60000.f;                   // exp2(x-60000) == 0 in f32
    if (n < 49 && m < 49) {
      int in_ = n / 7, jn = n % 7, im = m / 7, jm = m % 7;
      v = rpb[h * 169 + (im - in_ + 6) * 13 + (jm - jn + 6)] * 1.44269504f;
    }
    bias_t[h * 4096 + e] = (f16)v;
  }
}

// ---------------- 256x256 8-phase GEMM (Round-2 schedule; best measured) ----------
// HBOUT: epilogue writes head-blocked qkv [b][h][which][49][64].
// HBIN : A-source is head-blocked [b][h][49][64] (attnHB).
#define VM4 asm volatile("s_waitcnt vmcnt(4)" ::: "memory")
#define VM0 asm volatile("s_waitcnt vmcnt(0)" ::: "memory")
#define NOVM ((void)0)
#define NOSTG ((void)0)

template <bool HBIN>
__device__ __forceinline__ const f16* aptr(const f16* A, int row, int col, int K) {
  if (HBIN) {
    int bw = row / 49, n = row - bw * 49;
    int h = col >> 6, d = col & 63;
    return A + (size_t)bw * 50176 + h * 3136 + n * 64 + d;
  }
  return A + (size_t)row * K + col;
}

#define STAGEA(ROW0, COL0, LDSOFF)                                                 \
  {                                                                                \
    const f16* s0_ = aptr<HBIN>(A, (ROW0) + wid * 32 + srow, (COL0) + sce, K);     \
    __builtin_amdgcn_global_load_lds(G1P(s0_), L3P(lds + (LDSOFF) + wid * 2048), 16, 0, 0); \
    const f16* s1_ = aptr<HBIN>(A, (ROW0) + wid * 32 + srow + 16, (COL0) + sce, K); \
    __builtin_amdgcn_global_load_lds(G1P(s1_), L3P(lds + (LDSOFF) + wid * 2048 + 1024), 16, 0, 0); \
  }

#define STAGEB(ROW0, COL0, LDSOFF)                                                 \
  {                                                                                \
    const f16* s0_ = B + (size_t)((ROW0) + wid * 32 + srow) * K + ((COL0) + sce);  \
    __builtin_amdgcn_global_load_lds(G1P(s0_), L3P(lds + (LDSOFF) + wid * 2048), 16, 0, 0); \
    const f16* s1_ = s0_ + (size_t)16 * K;                                         \
    __builtin_amdgcn_global_load_lds(G1P(s1_), L3P(lds + (LDSOFF) + wid * 2048 + 1024), 16, 0, 0); \
  }

#define MFMA4(AREG, ROW)                                                           \
  acc[ROW][0] = __builtin_amdgcn_mfma_f32_16x16x32_f16(AREG, b0, acc[ROW][0], 0, 0, 0); \
  acc[ROW][1] = __builtin_amdgcn_mfma_f32_16x16x32_f16(AREG, b1, acc[ROW][1], 0, 0, 0); \
  acc[ROW][2] = __builtin_amdgcn_mfma_f32_16x16x32_f16(AREG, b2, acc[ROW][2], 0, 0, 0); \
  acc[ROW][3] = __builtin_amdgcn_mfma_f32_16x16x32_f16(AREG, b3, acc[ROW][3], 0, 0, 0);

#define PHASE(ABASE, BBASE, MH, STG, VMW)                                          \
  {                                                                                \
    f16x8 a0 = *(const f16x8*)((ABASE) + (wm * 128 + (MH) * 64 +  0 + l15) * 64 + swz); \
    f16x8 a1 = *(const f16x8*)((ABASE) + (wm * 128 + (MH) * 64 + 16 + l15) * 64 + swz); \
    f16x8 a2 = *(const f16x8*)((ABASE) + (wm * 128 + (MH) * 64 + 32 + l15) * 64 + swz); \
    f16x8 a3 = *(const f16x8*)((ABASE) + (wm * 128 + (MH) * 64 + 48 + l15) * 64 + swz); \
    if ((MH) == 0) {                                                               \
      b0 = *(const f16x8*)((BBASE) + (wn * 64 +  0 + l15) * 64 + swz);             \
      b1 = *(const f16x8*)((BBASE) + (wn * 64 + 16 + l15) * 64 + swz);             \
      b2 = *(const f16x8*)((BBASE) + (wn * 64 + 32 + l15) * 64 + swz);             \
      b3 = *(const f16x8*)((BBASE) + (wn * 64 + 48 + l15) * 64 + swz);             \
    }                                                                              \
    STG;                                                                           \
    __builtin_amdgcn_s_barrier();                                                  \
    asm volatile("s_waitcnt lgkmcnt(0)" ::: "memory");                             \
    __builtin_amdgcn_sched_barrier(0);                                             \
    __builtin_amdgcn_s_setprio(1);                                                 \
    MFMA4(a0, (MH) * 4 + 0) MFMA4(a1, (MH) * 4 + 1)                                \
    MFMA4(a2, (MH) * 4 + 2) MFMA4(a3, (MH) * 4 + 3)                                \
    __builtin_amdgcn_s_setprio(0);                                                 \
    VMW;                                                                           \
    __builtin_amdgcn_s_barrier();                                                  \
  }

template <typename OutT, bool HBOUT, bool HBIN>
__global__ __launch_bounds__(512, 2)
void gemm256(const f16* __restrict__ A, const f16* __restrict__ B,
             const float* __restrict__ bias, OutT* __restrict__ C,
             int N, int K, int ntiles_n) {
  __shared__ char lds[131072];
  const int tid = threadIdx.x;
  const int wid = tid >> 6, ln = tid & 63;
  const int l15 = ln & 15, lhi = ln >> 4;
  const int wm = wid >> 2, wn = wid & 3;
  const int srow = ln >> 2;
  const int sce = (((ln & 3) ^ ((ln >> 3) & 3)) << 3);
  const int swz = ((lhi ^ ((l15 >> 1) & 3)) << 4);

  const int nblk = gridDim.x;
  const int wg = (blockIdx.x & 7) * (nblk >> 3) + (blockIdx.x >> 3);
  const int bn = wg % ntiles_n, bm = wg / ntiles_n;
  const int m0 = bm * 256, n0 = bn * 256;

  f32x4 acc[8][4];
#pragma unroll
  for (int i = 0; i < 8; ++i)
#pragma unroll
    for (int j = 0; j < 4; ++j) acc[i][j] = (f32x4){0.f, 0.f, 0.f, 0.f};
  f16x8 b0, b1, b2, b3;

  STAGEA(m0, 0, 0);
  STAGEB(n0, 0, 32768);
  STAGEA(m0, 32, 16384);
  STAGEB(n0, 32, 49152);
  STAGEA(m0, 64, 65536);
  STAGEB(n0, 64, 98304);
  VM4;
  __builtin_amdgcn_s_barrier();

  for (int i = 0; i < 7; ++i) {
    const int cT1k1 = (2 * i + 1) * 64 + 32;
    const int cT2k0 = (2 * i + 2) * 64;
    const int cT2k1 = cT2k0 + 32;
    const int cT3k0 = (2 * i + 3) * 64;
    PHASE(lds + 0,      lds + 32768,  0, STAGEA(m0, cT1k1, 81920),  NOVM);
    PHASE(lds + 0,      lds + 32768,  1, STAGEB(n0, cT1k1, 114688), NOVM);
    PHASE(lds + 16384,  lds + 49152,  0, STAGEA(m0, cT2k0, 0),      NOVM);
    PHASE(lds + 16384,  lds + 49152,  1, STAGEB(n0, cT2k0, 32768),  VM4);
    PHASE(lds + 65536,  lds + 98304,  0, STAGEA(m0, cT2k1, 16384),  NOVM);
    PHASE(lds + 65536,  lds + 98304,  1, STAGEB(n0, cT2k1, 49152),  NOVM);
    PHASE(lds + 81920,  lds + 114688, 0, STAGEA(m0, cT3k0, 65536),  NOVM);
    PHASE(lds + 81920,  lds + 114688, 1, STAGEB(n0, cT3k0, 98304),  VM4);
  }
  PHASE(lds + 0,      lds + 32768,  0, STAGEA(m0, 15 * 64 + 32, 81920),  NOVM);
  PHASE(lds + 0,      lds + 32768,  1, STAGEB(n0, 15 * 64 + 32, 114688), NOVM);
  PHASE(lds + 16384,  lds + 49152,  0, NOSTG, NOVM);
  PHASE(lds + 16384,  lds + 49152,  1, NOSTG, VM0);
  PHASE(lds + 65536,  lds + 98304,  0, NOSTG, NOVM);
  PHASE(lds + 65536,  lds + 98304,  1, NOSTG, NOVM);
  PHASE(lds + 81920,  lds + 114688, 0, NOSTG, NOVM);
  PHASE(lds + 81920,  lds + 114688, 1, NOSTG, NOVM);

  float bv[4];
#pragma unroll
  for (int j = 0; j < 4; ++j) bv[j] = bias[n0 + wn * 64 + j * 16 + l15];
#pragma unroll
  for (int ii = 0; ii < 8; ++ii)
#pragma unroll
    for (int r = 0; r < 4; ++r) {
      int gr = m0 + wm * 128 + ii * 16 + lhi * 4 + r;
      if (HBOUT) {
        int bw = gr / 49, n = gr - bw * 49;   // window, token
#pragma unroll
        for (int j = 0; j < 4; ++j) {
          int gc = n0 + wn * 64 + j * 16 + l15;
          int which = gc >> 10, rem = gc & 1023;
          int h = rem >> 6, d = rem & 63;
          size_t addr = (((size_t)bw * 16 + h) * 3 + which) * 3136 + n * 64 + d;
          C[addr] = (OutT)(acc[ii][j][r] + bv[j]);
        }
      } else {
#pragma unroll
        for (int j = 0; j < 4; ++j) {
          int gc = n0 + wn * 64 + j * 16 + l15;
          C[(size_t)gr * N + gc] = (OutT)(acc[ii][j][r] + bv[j]);
        }
      }
    }
}

// ---------------- attention: 1 wave per (window, head), zero barriers ----------------
// (Round-10 compute; head-blocked qkv in, head-blocked attnHB out.)
// LDS 16KB: K then P [0,8K), Vt [8K,16K). All global loads issued up front;
// one vmcnt(0) drain; per-wave in-order DS gives all remaining ordering.
__global__ __launch_bounds__(64)
void attn_kernel(const f16* __restrict__ qkv,        // [b][h][q|k|v][49][64]
                 const f16* __restrict__ bias_t,     // f16 [16][m][n], pre-scaled log2e
                 f16* __restrict__ out) {             // [b][h][49][64]
  __shared__ char lds[16384];
  const int bh = blockIdx.x;
  const int h = bh & 15;
  const int ln = threadIdx.x;
  const int l15 = ln & 15, lhi = ln >> 4;
  const size_t qb = (size_t)bh * 3 * 3136;   // q block
  const size_t kb = qb + 3136;               // k block
  const size_t vb = qb + 6272;               // v block

  // --- issue K staging (8x global_load_lds; contiguous 128B rows) ---
  {
    int rA = ln >> 3, lc = ln & 7;
#pragma unroll
    for (int c = 0; c < 8; ++c) {
      int r = c * 8 + rA;
      int rc = r > 48 ? 48 : r;
      int ce = (lc ^ (r & 7)) << 3;
      const f16* g = qkv + kb + rc * 64 + ce;
      __builtin_amdgcn_global_load_lds(G1P(g), L3P(lds + c * 1024), 16, 0, 0);
    }
  }

  // --- issue V loads (8x b128; one contiguous block per wave) ---
  int rv = ln > 48 ? 48 : ln;
  const f16* vp = qkv + vb + rv * 64;
  f16x8 vr[8];
#pragma unroll
  for (int j = 0; j < 8; ++j) vr[j] = *(const f16x8*)(vp + j * 8);

  // --- issue Q loads (8x b128) ---
  f16x8 qf[4][2];
#pragma unroll
  for (int t = 0; t < 4; ++t) {
    int rq = t * 16 + l15;
    if (rq > 48) rq = 48;
    const f16* qp = qkv + qb + rq * 64 + lhi * 8;
    qf[t][0] = *(const f16x8*)(qp);
    qf[t][1] = *(const f16x8*)(qp + 32);
  }

  // --- issue bias loads (16x f16x4): bq[i][j] = bias[m=j*16+l15][n=i*16+lhi*4 ..+4) ---
  const f16* bb = bias_t + h * 4096;
  f16x4 bq[4][4];
#pragma unroll
  for (int i = 0; i < 4; ++i)
#pragma unroll
    for (int j = 0; j < 4; ++j)
      bq[i][j] = *(const f16x4*)(bb + (j * 16 + l15) * 64 + i * 16 + lhi * 4);

  // --- V transpose into Vt (compiler waits vr) ---
#pragma unroll
  for (int d = 0; d < 64; ++d)
    *(f16*)(lds + 8192 + d * 128 + ((ln * 2) ^ ((d & 7) << 4))) = vr[d >> 3][d & 7];

  // --- single drain: K LDS deposit + all reg loads complete ---
  asm volatile("s_waitcnt vmcnt(0)" ::: "memory");
  __builtin_amdgcn_sched_barrier(0);

  // --- S = Q @ K^T (K frags from LDS) ---
  f32x4 acc[4][4];
#pragma unroll
  for (int i = 0; i < 4; ++i)
#pragma unroll
    for (int j = 0; j < 4; ++j) acc[i][j] = (f32x4){0.f, 0.f, 0.f, 0.f};
#pragma unroll
  for (int kk = 0; kk < 2; ++kk) {
    f16x8 bf[4];
#pragma unroll
    for (int t = 0; t < 4; ++t) {
      int mr = t * 16 + l15;
      int pb = (kk * 64 + lhi * 16) ^ ((mr & 7) << 4);
      bf[t] = *(const f16x8*)(lds + mr * 128 + pb);
    }
    __builtin_amdgcn_s_setprio(1);
#pragma unroll
    for (int i = 0; i < 4; ++i)
#pragma unroll
      for (int j = 0; j < 4; ++j)
        acc[i][j] = __builtin_amdgcn_mfma_f32_16x16x32_f16(qf[i][kk], bf[j], acc[i][j], 0, 0, 0);
    __builtin_amdgcn_s_setprio(0);
  }

  // --- softmax (base-2; bias already in regs); P overwrites K region ---
  const float SC = 0.125f * 1.44269504f;
#pragma unroll
  for (int i = 0; i < 4; ++i) {
#pragma unroll
    for (int r = 0; r < 4; ++r) {
      int n = i * 16 + lhi * 4 + r;
      float lv[4];
#pragma unroll
      for (int j = 0; j < 4; ++j)
        lv[j] = acc[i][j][r] * SC + (float)bq[i][j][r];
      float Mx = fmaxf(fmaxf(lv[0], lv[1]), fmaxf(lv[2], lv[3]));
#pragma unroll
      for (int off = 1; off < 16; off <<= 1) Mx = fmaxf(Mx, __shfl_xor(Mx, off));
      float s = 0.f;
#pragma unroll
      for (int j = 0; j < 4; ++j) { lv[j] = exp2f(lv[j] - Mx); s += lv[j]; }
#pragma unroll
      for (int off = 1; off < 16; off <<= 1) s += __shfl_xor(s, off);
      float inv = 1.f / s;
#pragma unroll
      for (int j = 0; j < 4; ++j) {
        int m = j * 16 + l15;
        *(f16*)(lds + n * 128 + ((m * 2) ^ ((n & 7) << 4))) = (f16)(lv[j] * inv);
      }
    }
  }
  // per-wave in-order DS: P writes retire before the P reads below

  // --- O = P @ V ---
  f32x4 o[4][4];
#pragma unroll
  for (int i = 0; i < 4; ++i)
#pragma unroll
    for (int j = 0; j < 4; ++j) o[i][j] = (f32x4){0.f, 0.f, 0.f, 0.f};
#pragma unroll
  for (int kk = 0; kk < 2; ++kk) {
    f16x8 af[4], bf[4];
#pragma unroll
    for (int t = 0; t < 4; ++t) {
      int nr = t * 16 + l15;
      int pb = (kk * 64 + lhi * 16) ^ ((nr & 7) << 4);
      af[t] = *(const f16x8*)(lds + nr * 128 + pb);
      bf[t] = *(const f16x8*)(lds + 8192 + nr * 128 + pb);
    }
    __builtin_amdgcn_s_setprio(1);
#pragma unroll
    for (int i = 0; i < 4; ++i)
#pragma unroll
      for (int j = 0; j < 4; ++j)
        o[i][j] = __builtin_amdgcn_mfma_f32_16x16x32_f16(af[i], bf[j], o[i][j], 0, 0, 0);
    __builtin_amdgcn_s_setprio(0);
  }
  // store head-blocked: one contiguous 6.2KB run per block
  f16* ob = out + (size_t)bh * 3136;
#pragma unroll
  for (int i = 0; i < 4; ++i)
#pragma unroll
    for (int j = 0; j < 4; ++j)
#pragma unroll
      for (int r = 0; r < 4; ++r) {
        int n = i * 16 + lhi * 4 + r;
        if (n < 49)
          ob[n * 64 + j * 16 + l15] = (f16)o[i][j][r];
      }
}

extern "C" void kernel_launch(void* const* d_in, const int* in_sizes, int n_in,
                              void* d_out, int out_size, void* d_ws, size_t ws_size,
                              hipStream_t stream) {
  const float* x      = (const float*)d_in[0];  // [100352][1024]
  const float* qkv_w  = (const float*)d_in[1];  // [3072][1024]
  const float* qkv_b  = (const float*)d_in[2];  // [3072]
  const float* rpb    = (const float*)d_in[3];  // [16][13][13]
  const float* proj_w = (const float*)d_in[4];  // [1024][1024]
  const float* proj_b = (const float*)d_in[5];  // [1024]
  float* out = (float*)d_out;

  char* ws = (char*)d_ws;
  f16*   x16      = (f16*)(ws);                              // 205,520,896
  f16*   wq16     = (f16*)(ws + 205520896);                  //   6,291,456
  f16*   wp16     = (f16*)(ws + 211812352);                  //   2,097,152
  f16*   qkv16    = (f16*)(ws + 213909504);                  // 616,562,688 (head-blocked)
  f16*   attnHB   = (f16*)(ws + 830472192);                  // 205,520,896 (head-blocked)
  f16*   bias_t   = (f16*)(ws + 1035993088);                 //     131,072

  cvt_kernel<<<2048, 256, 0, stream>>>(x, x16, 102760448 / 4);
  cvt_kernel<<<1024, 256, 0, stream>>>(qkv_w, wq16, 3145728 / 4);
  cvt_kernel<<<512, 256, 0, stream>>>(proj_w, wp16, 1048576 / 4);
  bias_kernel<<<16, 64, 0, stream>>>(rpb, bias_t);

  // qkv = x @ qkv_w^T + qkv_b -> head-blocked [b][h][q|k|v][49][64] fp16
  gemm256<f16, true, false><<<4704, 512, 0, stream>>>(x16, wq16, qkv_b, qkv16, 3072, 1024, 12);
  // attention: 1 wave per (window, head); HB in, HB out
  attn_kernel<<<2048 * 16, 64, 0, stream>>>(qkv16, bias_t, attnHB);
  // out = attnHB @ proj_w^T + proj_b   [100352][1024] fp32 (HB A-read)
  gemm256<float, false, true><<<1568, 512, 0, stream>>>(attnHB, wp16, proj_b, out, 1024, 1024, 4);
}